// Round 10
// baseline (197.929 us; speedup 1.0000x reference)
//
#include <hip/hip_runtime.h>
#include <stdint.h>
#include <math.h>

// ============================================================================
// SliceKernel — exact JAX threefry slice sampler, single fused kernel.
// R10 = R9 with XD evicted from LDS -> 2 blocks/CU:
//   - LDS holds ONLY W (67.6 KB <= 80 KB) => 2 blocks x 16 waves = 8 waves/SIMD
//     (was 4; kernel is latency-bound there).  __launch_bounds__(1024,8)
//     pins VGPR <= 64 (R9 measured exactly 64).
//   - X read from global (16-lane broadcast per chain row, L1/L2-hot).
//   - D written to OUT (global) by dirs phase, read back in matvec/fallback.
//     Chain's D is touched only by its own wave (lockstep) -> the W barrier
//     (which drains vmcnt) is the only sync needed. Final x+u*d overwrites
//     D after the lane's own loads complete (data-dep ordering). Bit-exact.
//   - pk_fma (x,d) pairs packed from separate X/D loads (~8 movs/q).
// VALUE-PATH ARITHMETIC FROZEN (R1-R9, absmax 0.05078125):
//   dirs: u01 -> um -> sqrt2*erfinv -> /nrm; partial j, m-ascending; tree
//         pairing j^8,j^4,j^2,j^1 (shfl_xor 32,16,8,4 with j=lane>>2)
//   pot:  per-row k-ascending FMA chain; partials m-ascending; same tree
//   sampler: b-schedule, u updates, x+u*d exactly as reference
//   v_pk_fma_f32 per-component == __fmaf_rn (R8-verified)
// Decisions: f64 quadratic ps(u)=pot0-u g-u^2 h/2, eps guard, bit-exact
// chain fallback on near-ties (R3-R9: 0 flips).
// ============================================================================

#define BD 128   // feature dim D
#define NB 65536 // chains B
#define WS 132   // padded LDS row stride for W (floats)

typedef float f32x2 __attribute__((ext_vector_type(2)));
typedef struct { f32x2 lo, hi; } f32x2x2;

// both halves use src1 pair's LOW register:
#define PK_FMA_LO(acc, xd, wp) \
  asm("v_pk_fma_f32 %0, %1, %2, %0 op_sel_hi:[1,0,1]" \
      : "+v"(acc) : "v"(xd), "v"(wp))
// both halves use src1 pair's HIGH register:
#define PK_FMA_HI(acc, xd, wp) \
  asm("v_pk_fma_f32 %0, %1, %2, %0 op_sel:[0,1,0] op_sel_hi:[1,1,1]" \
      : "+v"(acc) : "v"(xd), "v"(wp))

// ---------------- threefry2x32 (host + device) ------------------------------
__host__ __device__ inline uint32_t rotl32(uint32_t v, int s) {
  return (v << s) | (v >> (32 - s));
}

__host__ __device__ inline void tf2x32(uint32_t k0, uint32_t k1,
                                       uint32_t c0, uint32_t c1,
                                       uint32_t* o0, uint32_t* o1) {
  uint32_t ks2 = k0 ^ k1 ^ 0x1BD11BDAu;
  uint32_t x0 = c0 + k0, x1 = c1 + k1;
#define TFR(r) x0 += x1; x1 = rotl32(x1, (r)); x1 ^= x0;
  TFR(13) TFR(15) TFR(26) TFR(6)
  x0 += k1;  x1 += ks2 + 1u;
  TFR(17) TFR(29) TFR(16) TFR(24)
  x0 += ks2; x1 += k0 + 2u;
  TFR(13) TFR(15) TFR(26) TFR(6)
  x0 += k0;  x1 += k1 + 3u;
  TFR(17) TFR(29) TFR(16) TFR(24)
  x0 += k1;  x1 += ks2 + 4u;
  TFR(13) TFR(15) TFR(26) TFR(6)
  x0 += ks2; x1 += k0 + 5u;
#undef TFR
  *o0 = x0; *o1 = x1;
}

__device__ inline uint32_t jbits(uint32_t k0, uint32_t k1, uint32_t n) {
  uint32_t a, b;
  tf2x32(k0, k1, 0u, n, &a, &b);
  return a ^ b;
}

// ---------------- XLA-exact scalar math -------------------------------------
__device__ inline float u01(uint32_t bits) {
  return __fsub_rn(__uint_as_float((bits >> 9) | 0x3f800000u), 1.0f);
}

__device__ inline float xla_log1p(float x) {
  float u  = __fadd_rn(x, 1.0f);
  float lg = (float)log((double)u);
  float sm = __fmul_rn(__fadd_rn(__fmul_rn(-0.5f, x), 1.0f), x);
  return (fabsf(x) < 1e-4f) ? sm : lg;
}

__device__ inline float xla_erfinv(float x) {
  float xx = __fmul_rn(x, x);
  float w  = -xla_log1p(-xx);
  float p;
  if (w < 5.0f) {
    float ww = __fsub_rn(w, 2.5f);
    p = 2.81022636e-08f;
    p = __fadd_rn(3.43273939e-07f,  __fmul_rn(p, ww));
    p = __fadd_rn(-3.5233877e-06f,  __fmul_rn(p, ww));
    p = __fadd_rn(-4.39150654e-06f, __fmul_rn(p, ww));
    p = __fadd_rn(0.00021858087f,   __fmul_rn(p, ww));
    p = __fadd_rn(-0.00125372503f,  __fmul_rn(p, ww));
    p = __fadd_rn(-0.00417768164f,  __fmul_rn(p, ww));
    p = __fadd_rn(0.246640727f,     __fmul_rn(p, ww));
    p = __fadd_rn(1.50140941f,      __fmul_rn(p, ww));
  } else {
    float ww = __fsub_rn(__fsqrt_rn(w), 3.0f);
    p = -0.000200214257f;
    p = __fadd_rn(0.000100950558f,  __fmul_rn(p, ww));
    p = __fadd_rn(0.00134934322f,   __fmul_rn(p, ww));
    p = __fadd_rn(-0.00367342844f,  __fmul_rn(p, ww));
    p = __fadd_rn(0.00573950773f,   __fmul_rn(p, ww));
    p = __fadd_rn(-0.0076224613f,   __fmul_rn(p, ww));
    p = __fadd_rn(0.00943887047f,   __fmul_rn(p, ww));
    p = __fadd_rn(1.00167406f,      __fmul_rn(p, ww));
    p = __fadd_rn(2.83297682f,      __fmul_rn(p, ww));
  }
  return __fmul_rn(p, x);
}

// ---------------- bit-exact chain potential (fallback path) -----------------
// x,d from GLOBAL (chain-row broadcast, cache-hot). Same arithmetic as R1-R9.
__device__ __attribute__((always_inline)) inline float potential16(
    const float* __restrict__ xrow, const float* __restrict__ drow,
    const float* __restrict__ wr, float coef) {
  float z[8] = {0.f, 0.f, 0.f, 0.f, 0.f, 0.f, 0.f, 0.f};
#pragma unroll 2
  for (int q = 0; q < 32; ++q) {
    float4 xq = *(const float4*)(xrow + q * 4);
    float4 dq = *(const float4*)(drow + q * 4);
    float c0 = __fadd_rn(xq.x, __fmul_rn(coef, dq.x));
    float c1 = __fadd_rn(xq.y, __fmul_rn(coef, dq.y));
    float c2 = __fadd_rn(xq.z, __fmul_rn(coef, dq.z));
    float c3 = __fadd_rn(xq.w, __fmul_rn(coef, dq.w));
#pragma unroll
    for (int m = 0; m < 8; ++m) {
      float4 wv = *(const float4*)(wr + m * (16 * WS) + q * 4);
      z[m] = __fmaf_rn(c0, wv.x, z[m]);
      z[m] = __fmaf_rn(c1, wv.y, z[m]);
      z[m] = __fmaf_rn(c2, wv.z, z[m]);
      z[m] = __fmaf_rn(c3, wv.w, z[m]);
    }
  }
  float pr = 0.0f;
#pragma unroll
  for (int m = 0; m < 8; ++m) pr = __fadd_rn(pr, __fmul_rn(z[m], z[m]));
#pragma unroll
  for (int msk = 32; msk >= 4; msk >>= 1)
    pr = __fadd_rn(pr, __shfl_xor(pr, msk));
  return __fmul_rn(-0.5f, pr);
}

// certainty margin: >=3x worst-case chain-vs-quadratic rounding discrepancy
__device__ inline double epsb(float u) {
  double au = fabs((double)u);
  return 4e-4 + 8e-5 * au + 8e-6 * au * au;
}

// ---------------- the single fused kernel -----------------------------------
struct KeyArgs {
  uint32_t ky0, ky1;    // k_y
  uint32_t ku0, ku1;    // k_u0
  uint32_t kd0, kd1;    // k_dir
  uint32_t ksh0, ksh1;  // k_shr (shrink keys derived on device)
};

__global__ __launch_bounds__(1024, 8) void slice_fused_kernel(
    const float* __restrict__ X, const float* __restrict__ Wg,
    float* __restrict__ OUT, KeyArgs ka) {
  __shared__ __align__(16) float Wl[128 * WS];  // 67,584 B — ONLY LDS use

  const int tid   = threadIdx.x;
  const int cbase = blockIdx.x * 64;

  // ---- stage W (padded rows) ----
  for (int i = tid; i < 128 * 32; i += 1024) {
    int r = i >> 5, q = i & 31;
    *(float4*)&Wl[r * WS + q * 4] = ((const float4*)Wg)[i];
  }

  const int wave = tid >> 6, lane = tid & 63;
  const int c    = lane & 3;          // chain-in-wave
  const int j    = lane >> 2;         // partial index 0..15 (rows 16m+j)
  const int cl   = wave * 4 + c;      // chain local (0..63)
  const uint32_t chain = (uint32_t)(cbase + cl);

  const float* xrow = X   + (size_t)chain * BD;
  float*       drow = OUT + (size_t)chain * BD;  // D staged in OUT

  // ---- lane-parallel sampler RNG (overlaps staging latency) ----
  float uA, uB;
  {
    uint32_t a0, a1;
    tf2x32(ka.ksh0, ka.ksh1, 0u, (uint32_t)j, &a0, &a1);
    uA = u01(jbits(a0, a1, chain));
    uint32_t d0, d1;
    tf2x32(ka.ksh0, ka.ksh1, 0u, 16u + (uint32_t)j, &d0, &d1);
    uint32_t bk0 = (j < 8) ? d0 : (j == 8 ? ka.ky0 : ka.ku0);
    uint32_t bk1 = (j < 8) ? d1 : (j == 8 ? ka.ky1 : ka.ku1);
    uB = u01(jbits(bk0, bk1, chain));
  }

  // ---- dirs phase: vm -> D = vm/nrm stored to OUT (global) ----
  {
    const float LO    = __uint_as_float(0xBF7FFFFFu);
    const float SQRT2 = __uint_as_float(0x3FB504F3u);
    float vm[8];
#pragma unroll
    for (int m = 0; m < 8; ++m) {
      uint32_t n = chain * 128u + (uint32_t)(16 * m + j);
      float f  = u01(jbits(ka.kd0, ka.kd1, n));
      float um = fmaxf(LO, __fadd_rn(__fmul_rn(f, 2.0f), LO));
      vm[m] = __fmul_rn(SQRT2, xla_erfinv(um));
    }
    float pr = 0.0f;
#pragma unroll
    for (int m = 0; m < 8; ++m) pr = __fadd_rn(pr, __fmul_rn(vm[m], vm[m]));
#pragma unroll
    for (int msk = 32; msk >= 4; msk >>= 1)
      pr = __fadd_rn(pr, __shfl_xor(pr, msk));
    float nrm = __fsqrt_rn(pr);
#pragma unroll
    for (int m = 0; m < 8; ++m)
      drow[16 * m + j] = vm[m] / nrm;
  }

  // barrier: completes W staging AND drains the D stores (vmcnt(0) semantics)
  __syncthreads();

  const float* wr = &Wl[j * WS];      // row 16m+j at wr + m*16*WS

  // ---- packed fused matvec: zab[m] = (za[m], zb[m]) ----
  f32x2 zab[8];
#pragma unroll
  for (int m = 0; m < 8; ++m) zab[m] = (f32x2){0.0f, 0.0f};
#pragma unroll 2
  for (int q = 0; q < 32; ++q) {
    float4 xq = *(const float4*)(xrow + q * 4);
    float4 dq = *(const float4*)(drow + q * 4);
    f32x2 xd0 = {xq.x, dq.x}, xd1 = {xq.y, dq.y};
    f32x2 xd2 = {xq.z, dq.z}, xd3 = {xq.w, dq.w};
#pragma unroll
    for (int m = 0; m < 8; ++m) {
      const f32x2x2 wq = *(const f32x2x2*)(wr + m * (16 * WS) + q * 4);  // b128
      PK_FMA_LO(zab[m], xd0, wq.lo);   // * wx
      PK_FMA_HI(zab[m], xd1, wq.lo);   // * wy
      PK_FMA_LO(zab[m], xd2, wq.hi);   // * wz
      PK_FMA_HI(zab[m], xd3, wq.hi);   // * ww
    }
  }

  // pot0: chain-exact f32 reduce (partials m-ascending + tree)
  float pr0 = 0.0f;
#pragma unroll
  for (int m = 0; m < 8; ++m) pr0 = __fadd_rn(pr0, __fmul_rn(zab[m].x, zab[m].x));
#pragma unroll
  for (int msk = 32; msk >= 4; msk >>= 1)
    pr0 = __fadd_rn(pr0, __shfl_xor(pr0, msk));
  float pot0 = __fmul_rn(-0.5f, pr0);

  // g = a·b, h = ‖b‖² in f64 (surrogate only; order-free)
  double gl = 0.0, hl = 0.0;
#pragma unroll
  for (int m = 0; m < 8; ++m) {
    gl += (double)zab[m].x * (double)zab[m].y;
    hl += (double)zab[m].y * (double)zab[m].y;
  }
#pragma unroll
  for (int msk = 32; msk >= 4; msk >>= 1) {
    gl += __shfl_xor(gl, msk);
    hl += __shfl_xor(hl, msk);
  }
  const double g = gl, h = hl;
  const double potd0 = (double)pot0;

  // ---- y = log1p(-U) + pot0 (exact f32); Uy from lane c+32 ----
  float Uy = __shfl(uB, c + 32);
  float y  = __fadd_rn(xla_log1p(-Uy), pot0);
  const double yd = (double)y;
  bool mask0 = (y < pot0);

  // ---- bracket expansion ----
  float lb = 0.0f, ub = 0.0f;
#pragma unroll 1
  for (int side = 0; side < 2; ++side) {
    bool m = mask0;
    float b = 0.0f, pw = 1.0f;
#pragma unroll 1
    for (int i = 0; i < 16; ++i) {
      if (!__any((int)m)) break;
      float step = __fmul_rn(0.1f, pw);
      pw = __fmul_rn(pw, 1.5f);
      if (m) b = side ? __fadd_rn(b, step) : __fsub_rn(b, step);
      double bd   = (double)b;
      double diff = (potd0 - bd * g - 0.5 * bd * bd * h) - yd;
      bool need = m && (fabs(diff) <= epsb(b));
      float pe = 0.0f;
      if (__any((int)need)) pe = potential16(xrow, drow, wr, b);
      bool cont = need ? (y < pe) : (diff > 0.0);
      m = m && cont;
    }
    if (side == 0) lb = b; else ub = b;
  }

  // ---- initial proposal; U0 from lane c+36 ----
  float U0 = __shfl(uB, c + 36);
  float u  = __fadd_rn(__fmul_rn(U0, __fsub_rn(ub, lb)), lb);
  bool rej;
  {
    double ud   = (double)u;
    double diff = (potd0 - ud * g - 0.5 * ud * ud * h) - yd;
    bool need = fabs(diff) <= epsb(u);
    float pe = 0.0f;
    if (__any((int)need)) pe = potential16(xrow, drow, wr, u);
    rej = need ? (pe < y) : (diff < 0.0);
  }

  // ---- shrinkage; Ut[t] broadcast from lane c+4*slot ----
#pragma unroll 1
  for (int t = 0; t < 24; ++t) {
    if (!__any((int)rej)) break;
    float Ut = (t < 16) ? __shfl(uA, c + 4 * t) : __shfl(uB, c + 4 * (t - 16));
    if (rej) {
      if (u < 0.0f) lb = u; else ub = u;
      u = __fadd_rn(__fmul_rn(Ut, __fsub_rn(ub, lb)), lb);
    }
    double ud   = (double)u;
    double diff = (potd0 - ud * g - 0.5 * ud * ud * h) - yd;
    bool need = rej && (fabs(diff) <= epsb(u));
    float pe = 0.0f;
    if (__any((int)need)) pe = potential16(xrow, drow, wr, u);
    bool rj = need ? (pe < y) : (diff < 0.0);
    rej = rej && rj;
  }

  // ---- x_new = x + u*dirs (exact); lane (c,j) owns quads 2j, 2j+1 ----
  // loads complete (data dep) before the store overwrites D with the result.
#pragma unroll
  for (int hh = 0; hh < 2; ++hh) {
    int q2 = j * 2 + hh;
    float4 xq = *(const float4*)(xrow + q2 * 4);
    float4 dq = *(const float4*)(drow + q2 * 4);
    float4 o;
    o.x = __fadd_rn(xq.x, __fmul_rn(u, dq.x));
    o.y = __fadd_rn(xq.y, __fmul_rn(u, dq.y));
    o.z = __fadd_rn(xq.z, __fmul_rn(u, dq.z));
    o.w = __fadd_rn(xq.w, __fmul_rn(u, dq.w));
    *(float4*)(drow + q2 * 4) = o;
  }
}

// ---------------- launcher ---------------------------------------------------
extern "C" void kernel_launch(void* const* d_in, const int* in_sizes, int n_in,
                              void* d_out, int out_size, void* d_ws, size_t ws_size,
                              hipStream_t stream) {
  (void)in_sizes; (void)n_in; (void)d_ws; (void)ws_size; (void)out_size;
  const float* x = (const float*)d_in[0];
  const float* W = (const float*)d_in[1];
  float* out = (float*)d_out;

  const uint32_t R0 = 0u, R1 = 42u;  // jax.random.key(42)
  KeyArgs ka;
  tf2x32(R0, R1, 0u, 0u, &ka.ky0, &ka.ky1);
  tf2x32(R0, R1, 0u, 1u, &ka.kd0, &ka.kd1);
  tf2x32(R0, R1, 0u, 2u, &ka.ku0, &ka.ku1);
  tf2x32(R0, R1, 0u, 3u, &ka.ksh0, &ka.ksh1);

  slice_fused_kernel<<<dim3(NB / 64), dim3(1024), 0, stream>>>(x, W, out, ka);
}

// Round 11
// 136.524 us; speedup vs baseline: 1.4498x; 1.4498x over previous
//
#include <hip/hip_runtime.h>
#include <stdint.h>
#include <math.h>

// ============================================================================
// SliceKernel — exact JAX threefry slice sampler, single fused kernel.
// R11 = R8 (best, 138.6us) + two fixes:
//  (a) W LDS reads back to ONE ds_read_b128 (union float4 <-> f32x2 halves,
//      register-adjacent, no movs) -> kills R8's 2.6M bank-conflict regression
//      while keeping v_pk_fma_f32 (pair operands, op_sel broadcast).
//  (b) bracket/shrink decisions evaluated in f32: py = pot0-y (f32, near-
//      Sterbenz exact), gf/hf = fl32(g/h); widened certainty band
//      eps32 = 6e-4 + 1.5e-4|u| + 1.2e-5u^2 covers chain-vs-quadratic
//      (~1.2e-4(1+|u|)) + f32 eval error with >=3x margin. Near-ties still
//      take the bit-exact chain fallback -> decisions identical.
// R10 lesson: launch_bounds(1024,8) crushed VGPR to 32 (spills) and global
// XD round-trip killed it (VALUBusy 51%). LDS-resident W+XD at 4 waves/SIMD
// is the right structure; kernel is ~issue-bound there.
// VALUE-PATH ARITHMETIC FROZEN (R1-R9, absmax 0.05078125):
//   dirs: u01 -> um -> sqrt2*erfinv -> /nrm; partial j, m-ascending; tree
//         pairing j^8,j^4,j^2,j^1 (shfl_xor 32,16,8,4 with j=lane>>2)
//   pot:  per-row k-ascending FMA chain; partials m-ascending; same tree
//   sampler: b-schedule, u updates, x+u*d exactly as reference
//   v_pk_fma_f32 per-component == __fmaf_rn (R8-verified)
// ============================================================================

#define BD 128   // feature dim D
#define NB 65536 // chains B
#define WS 132   // padded LDS row stride for W (floats)
#define XDS 130  // XD stride in float2 units

typedef float f32x2 __attribute__((ext_vector_type(2)));
union W4 { float4 v4; f32x2 h[2]; };  // one b128 load, two pk operands

// both halves use src1 pair's LOW register:
#define PK_FMA_LO(acc, xd, wp) \
  asm("v_pk_fma_f32 %0, %1, %2, %0 op_sel_hi:[1,0,1]" \
      : "+v"(acc) : "v"(xd), "v"(wp))
// both halves use src1 pair's HIGH register:
#define PK_FMA_HI(acc, xd, wp) \
  asm("v_pk_fma_f32 %0, %1, %2, %0 op_sel:[0,1,0] op_sel_hi:[1,1,1]" \
      : "+v"(acc) : "v"(xd), "v"(wp))

// ---------------- threefry2x32 (host + device) ------------------------------
__host__ __device__ inline uint32_t rotl32(uint32_t v, int s) {
  return (v << s) | (v >> (32 - s));
}

__host__ __device__ inline void tf2x32(uint32_t k0, uint32_t k1,
                                       uint32_t c0, uint32_t c1,
                                       uint32_t* o0, uint32_t* o1) {
  uint32_t ks2 = k0 ^ k1 ^ 0x1BD11BDAu;
  uint32_t x0 = c0 + k0, x1 = c1 + k1;
#define TFR(r) x0 += x1; x1 = rotl32(x1, (r)); x1 ^= x0;
  TFR(13) TFR(15) TFR(26) TFR(6)
  x0 += k1;  x1 += ks2 + 1u;
  TFR(17) TFR(29) TFR(16) TFR(24)
  x0 += ks2; x1 += k0 + 2u;
  TFR(13) TFR(15) TFR(26) TFR(6)
  x0 += k0;  x1 += k1 + 3u;
  TFR(17) TFR(29) TFR(16) TFR(24)
  x0 += k1;  x1 += ks2 + 4u;
  TFR(13) TFR(15) TFR(26) TFR(6)
  x0 += ks2; x1 += k0 + 5u;
#undef TFR
  *o0 = x0; *o1 = x1;
}

__device__ inline uint32_t jbits(uint32_t k0, uint32_t k1, uint32_t n) {
  uint32_t a, b;
  tf2x32(k0, k1, 0u, n, &a, &b);
  return a ^ b;
}

// ---------------- XLA-exact scalar math -------------------------------------
__device__ inline float u01(uint32_t bits) {
  return __fsub_rn(__uint_as_float((bits >> 9) | 0x3f800000u), 1.0f);
}

__device__ inline float xla_log1p(float x) {
  float u  = __fadd_rn(x, 1.0f);
  float lg = (float)log((double)u);
  float sm = __fmul_rn(__fadd_rn(__fmul_rn(-0.5f, x), 1.0f), x);
  return (fabsf(x) < 1e-4f) ? sm : lg;
}

__device__ inline float xla_erfinv(float x) {
  float xx = __fmul_rn(x, x);
  float w  = -xla_log1p(-xx);
  float p;
  if (w < 5.0f) {
    float ww = __fsub_rn(w, 2.5f);
    p = 2.81022636e-08f;
    p = __fadd_rn(3.43273939e-07f,  __fmul_rn(p, ww));
    p = __fadd_rn(-3.5233877e-06f,  __fmul_rn(p, ww));
    p = __fadd_rn(-4.39150654e-06f, __fmul_rn(p, ww));
    p = __fadd_rn(0.00021858087f,   __fmul_rn(p, ww));
    p = __fadd_rn(-0.00125372503f,  __fmul_rn(p, ww));
    p = __fadd_rn(-0.00417768164f,  __fmul_rn(p, ww));
    p = __fadd_rn(0.246640727f,     __fmul_rn(p, ww));
    p = __fadd_rn(1.50140941f,      __fmul_rn(p, ww));
  } else {
    float ww = __fsub_rn(__fsqrt_rn(w), 3.0f);
    p = -0.000200214257f;
    p = __fadd_rn(0.000100950558f,  __fmul_rn(p, ww));
    p = __fadd_rn(0.00134934322f,   __fmul_rn(p, ww));
    p = __fadd_rn(-0.00367342844f,  __fmul_rn(p, ww));
    p = __fadd_rn(0.00573950773f,   __fmul_rn(p, ww));
    p = __fadd_rn(-0.0076224613f,   __fmul_rn(p, ww));
    p = __fadd_rn(0.00943887047f,   __fmul_rn(p, ww));
    p = __fadd_rn(1.00167406f,      __fmul_rn(p, ww));
    p = __fadd_rn(2.83297682f,      __fmul_rn(p, ww));
  }
  return __fmul_rn(p, x);
}

// ---------------- bit-exact chain potential (fallback path) -----------------
__device__ __attribute__((always_inline)) inline float potential16(
    const f32x2* __restrict__ xdr, const float* __restrict__ wr, float coef) {
  float z[8] = {0.f, 0.f, 0.f, 0.f, 0.f, 0.f, 0.f, 0.f};
#pragma unroll 2
  for (int q = 0; q < 32; ++q) {
    float4 p01 = *(const float4*)(xdr + q * 4);
    float4 p23 = *(const float4*)(xdr + q * 4 + 2);
    float c0 = __fadd_rn(p01.x, __fmul_rn(coef, p01.y));
    float c1 = __fadd_rn(p01.z, __fmul_rn(coef, p01.w));
    float c2 = __fadd_rn(p23.x, __fmul_rn(coef, p23.y));
    float c3 = __fadd_rn(p23.z, __fmul_rn(coef, p23.w));
#pragma unroll
    for (int m = 0; m < 8; ++m) {
      float4 wv = *(const float4*)(wr + m * (16 * WS) + q * 4);
      z[m] = __fmaf_rn(c0, wv.x, z[m]);
      z[m] = __fmaf_rn(c1, wv.y, z[m]);
      z[m] = __fmaf_rn(c2, wv.z, z[m]);
      z[m] = __fmaf_rn(c3, wv.w, z[m]);
    }
  }
  float pr = 0.0f;
#pragma unroll
  for (int m = 0; m < 8; ++m) pr = __fadd_rn(pr, __fmul_rn(z[m], z[m]));
#pragma unroll
  for (int msk = 32; msk >= 4; msk >>= 1)
    pr = __fadd_rn(pr, __shfl_xor(pr, msk));
  return __fmul_rn(-0.5f, pr);
}

// f32 certainty band: covers chain-vs-quadratic discrepancy (~1.2e-4(1+|u|))
// + f32 surrogate evaluation error, with >=3x margin.
__device__ inline float eps32(float u) {
  float au = fabsf(u);
  return __fmaf_rn(au, __fmaf_rn(au, 1.2e-5f, 1.5e-4f), 6e-4f);
}

// ---------------- the single fused kernel -----------------------------------
struct KeyArgs {
  uint32_t ky0, ky1;   // k_y
  uint32_t ku0, ku1;   // k_u0
  uint32_t kd0, kd1;   // k_dir
  uint32_t ks[48];     // 24 shrink keys
};

__global__ __launch_bounds__(1024, 1) void slice_fused_kernel(
    const float* __restrict__ X, const float* __restrict__ Wg,
    float* __restrict__ OUT, KeyArgs ka) {
  __shared__ __align__(16) float Wl[128 * WS];    // 67,584 B
  __shared__ __align__(16) f32x2 XDl[64 * XDS];   // 66,560 B (total 134,144)

  const int tid   = threadIdx.x;
  const int cbase = blockIdx.x * 64;

  // ---- stage W (padded rows) ----
  for (int i = tid; i < 128 * 32; i += 1024) {
    int r = i >> 5, q = i & 31;
    *(float4*)&Wl[r * WS + q * 4] = ((const float4*)Wg)[i];
  }
  // ---- stage X into .x slots of XD ----
  for (int i = tid; i < 64 * 32; i += 1024) {
    int cc = i >> 5, q = i & 31;
    float4 xv = ((const float4*)(X + (size_t)(cbase + cc) * BD))[q];
    float* b0 = (float*)&XDl[cc * XDS + q * 4];
    b0[0] = xv.x; b0[2] = xv.y; b0[4] = xv.z; b0[6] = xv.w;
  }

  const int wave = tid >> 6, lane = tid & 63;
  const int c    = lane & 3;          // chain-in-wave
  const int j    = lane >> 2;         // partial index 0..15 (rows 16m+j)
  const int cl   = wave * 4 + c;      // chain local (0..63)
  const uint32_t chain = (uint32_t)(cbase + cl);

  // ---- dirs phase (registers; writes .y slots of XD) ----
  {
    const float LO    = __uint_as_float(0xBF7FFFFFu);
    const float SQRT2 = __uint_as_float(0x3FB504F3u);
    float vm[8];
#pragma unroll
    for (int m = 0; m < 8; ++m) {
      uint32_t n = chain * 128u + (uint32_t)(16 * m + j);
      float f  = u01(jbits(ka.kd0, ka.kd1, n));
      float um = fmaxf(LO, __fadd_rn(__fmul_rn(f, 2.0f), LO));
      vm[m] = __fmul_rn(SQRT2, xla_erfinv(um));
    }
    float pr = 0.0f;
#pragma unroll
    for (int m = 0; m < 8; ++m) pr = __fadd_rn(pr, __fmul_rn(vm[m], vm[m]));
#pragma unroll
    for (int msk = 32; msk >= 4; msk >>= 1)
      pr = __fadd_rn(pr, __shfl_xor(pr, msk));
    float nrm = __fsqrt_rn(pr);
#pragma unroll
    for (int m = 0; m < 8; ++m)
      ((float*)&XDl[cl * XDS + 16 * m + j])[1] = vm[m] / nrm;
  }

  __syncthreads();  // single block barrier: staging + dirs complete

  const f32x2* xdr = &XDl[cl * XDS];
  const float* wr  = &Wl[j * WS];     // row 16m+j at wr + m*16*WS

  // ---- packed fused matvec: zab[m] = (za[m], zb[m]) ----
  f32x2 zab[8];
#pragma unroll
  for (int m = 0; m < 8; ++m) zab[m] = (f32x2){0.0f, 0.0f};
#pragma unroll 2
  for (int q = 0; q < 32; ++q) {
    float4 p01 = *(const float4*)(xdr + q * 4);
    float4 p23 = *(const float4*)(xdr + q * 4 + 2);
    f32x2 xd0 = {p01.x, p01.y}, xd1 = {p01.z, p01.w};
    f32x2 xd2 = {p23.x, p23.y}, xd3 = {p23.z, p23.w};
#pragma unroll
    for (int m = 0; m < 8; ++m) {
      W4 wq;
      wq.v4 = *(const float4*)(wr + m * (16 * WS) + q * 4);  // ONE b128
      PK_FMA_LO(zab[m], xd0, wq.h[0]);   // * wv.x
      PK_FMA_HI(zab[m], xd1, wq.h[0]);   // * wv.y
      PK_FMA_LO(zab[m], xd2, wq.h[1]);   // * wv.z
      PK_FMA_HI(zab[m], xd3, wq.h[1]);   // * wv.w
    }
  }

  // pot0: chain-exact f32 reduce (partials m-ascending + tree)
  float pr0 = 0.0f;
#pragma unroll
  for (int m = 0; m < 8; ++m) pr0 = __fadd_rn(pr0, __fmul_rn(zab[m].x, zab[m].x));
#pragma unroll
  for (int msk = 32; msk >= 4; msk >>= 1)
    pr0 = __fadd_rn(pr0, __shfl_xor(pr0, msk));
  float pot0 = __fmul_rn(-0.5f, pr0);

  // g = a·b, h = ‖b‖² in f64 (order-free), then f32 for the decision path
  double gl = 0.0, hl = 0.0;
#pragma unroll
  for (int m = 0; m < 8; ++m) {
    gl += (double)zab[m].x * (double)zab[m].y;
    hl += (double)zab[m].y * (double)zab[m].y;
  }
#pragma unroll
  for (int msk = 32; msk >= 4; msk >>= 1) {
    gl += __shfl_xor(gl, msk);
    hl += __shfl_xor(hl, msk);
  }
  const float gf = (float)gl;
  const float hf = (float)(0.5 * hl);

  // ---- y = log1p(-U) + pot0 (exact f32) ----
  float Uy = u01(jbits(ka.ky0, ka.ky1, chain));
  float y  = __fadd_rn(xla_log1p(-Uy), pot0);
  // py = pot0 - y : near-Sterbenz, error <= 2e-6 (covered by eps32)
  const float py = __fsub_rn(pot0, y);
  bool mask0 = (y < pot0);

  // f32 surrogate: diff(u) = py - u*gf - u^2*hf   (>0 <=> y < ps(u))
#define SDIFF(u) (py - (u) * gf - (u) * (u) * hf)

  // ---- bracket expansion ----
  float lb = 0.0f, ub = 0.0f;
#pragma unroll 1
  for (int side = 0; side < 2; ++side) {
    bool m = mask0;
    float b = 0.0f, pw = 1.0f;
#pragma unroll 1
    for (int i = 0; i < 16; ++i) {
      if (!__any((int)m)) break;
      float step = __fmul_rn(0.1f, pw);
      pw = __fmul_rn(pw, 1.5f);
      if (m) b = side ? __fadd_rn(b, step) : __fsub_rn(b, step);
      float diff = SDIFF(b);
      bool need = m && (fabsf(diff) <= eps32(b));
      float pe = 0.0f;
      if (__any((int)need)) pe = potential16(xdr, wr, b);
      bool cont = need ? (y < pe) : (diff > 0.0f);
      m = m && cont;
    }
    if (side == 0) lb = b; else ub = b;
  }

  // ---- initial proposal ----
  float U0 = u01(jbits(ka.ku0, ka.ku1, chain));
  float u  = __fadd_rn(__fmul_rn(U0, __fsub_rn(ub, lb)), lb);
  bool rej;
  {
    float diff = SDIFF(u);
    bool need = fabsf(diff) <= eps32(u);
    float pe = 0.0f;
    if (__any((int)need)) pe = potential16(xdr, wr, u);
    rej = need ? (pe < y) : (diff < 0.0f);
  }

  // ---- shrinkage ----
#pragma unroll 1
  for (int t = 0; t < 24; ++t) {
    if (!__any((int)rej)) break;
    if (rej) {
      if (u < 0.0f) lb = u; else ub = u;
      float Ut = u01(jbits(ka.ks[2 * t], ka.ks[2 * t + 1], chain));
      u = __fadd_rn(__fmul_rn(Ut, __fsub_rn(ub, lb)), lb);
    }
    float diff = SDIFF(u);
    bool need = rej && (fabsf(diff) <= eps32(u));
    float pe = 0.0f;
    if (__any((int)need)) pe = potential16(xdr, wr, u);
    bool rj = need ? (pe < y) : (diff < 0.0f);
    rej = rej && rj;
  }
#undef SDIFF

  // ---- x_new = x + u*dirs (exact); lane (c,j) writes quads 2j, 2j+1 ----
  float* orow = OUT + (size_t)chain * BD;
#pragma unroll
  for (int hh = 0; hh < 2; ++hh) {
    int q2 = j * 2 + hh;
    float4 p01 = *(const float4*)(xdr + q2 * 4);
    float4 p23 = *(const float4*)(xdr + q2 * 4 + 2);
    float4 o;
    o.x = __fadd_rn(p01.x, __fmul_rn(u, p01.y));
    o.y = __fadd_rn(p01.z, __fmul_rn(u, p01.w));
    o.z = __fadd_rn(p23.x, __fmul_rn(u, p23.y));
    o.w = __fadd_rn(p23.z, __fmul_rn(u, p23.w));
    *(float4*)&orow[q2 * 4] = o;
  }
}

// ---------------- launcher ---------------------------------------------------
extern "C" void kernel_launch(void* const* d_in, const int* in_sizes, int n_in,
                              void* d_out, int out_size, void* d_ws, size_t ws_size,
                              hipStream_t stream) {
  (void)in_sizes; (void)n_in; (void)d_ws; (void)ws_size; (void)out_size;
  const float* x = (const float*)d_in[0];
  const float* W = (const float*)d_in[1];
  float* out = (float*)d_out;

  const uint32_t R0 = 0u, R1 = 42u;  // jax.random.key(42)
  uint32_t ky0, ky1, kd0, kd1, ku0, ku1, ksh0, ksh1;
  tf2x32(R0, R1, 0u, 0u, &ky0, &ky1);
  tf2x32(R0, R1, 0u, 1u, &kd0, &kd1);
  tf2x32(R0, R1, 0u, 2u, &ku0, &ku1);
  tf2x32(R0, R1, 0u, 3u, &ksh0, &ksh1);

  KeyArgs ka;
  ka.ky0 = ky0; ka.ky1 = ky1; ka.ku0 = ku0; ka.ku1 = ku1;
  ka.kd0 = kd0; ka.kd1 = kd1;
  for (uint32_t t = 0; t < 24; ++t) {
    uint32_t a, b;
    tf2x32(ksh0, ksh1, 0u, t, &a, &b);
    ka.ks[2 * t] = a; ka.ks[2 * t + 1] = b;
  }

  slice_fused_kernel<<<dim3(NB / 64), dim3(1024), 0, stream>>>(x, W, out, ka);
}